// Round 1
// baseline (911.082 us; speedup 1.0000x reference)
//
#include <hip/hip_runtime.h>
#include <stdint.h>

// ---------------- problem constants ----------------
#define SEQ   500
#define BATCH 32
#define DIN   256
#define DM    512
#define NH    8
#define NL    2
#define DF    2048
#define WINSZ 100
#define HD    64          // DM/NH
#define ROWS  (SEQ*BATCH) // 16000

typedef __bf16 bf16x8 __attribute__((ext_vector_type(8)));
typedef float  f32x4  __attribute__((ext_vector_type(4)));

// ---------------- helpers ----------------
__device__ __forceinline__ unsigned short bfbits(float f) {
    unsigned int u = __builtin_bit_cast(unsigned int, f);
    u = u + 0x7fffu + ((u >> 16) & 1u);           // RNE
    return (unsigned short)(u >> 16);
}
__device__ __forceinline__ unsigned int pack2(float a, float b) {
    return (unsigned int)bfbits(a) | ((unsigned int)bfbits(b) << 16);
}
__device__ __forceinline__ float blo(unsigned int u) { return __builtin_bit_cast(float, u << 16); }
__device__ __forceinline__ float bhi(unsigned int u) { return __builtin_bit_cast(float, u & 0xffff0000u); }

__device__ __forceinline__ float dot8(uint4 q, uint4 k, float s) {
    s = fmaf(blo(q.x), blo(k.x), s); s = fmaf(bhi(q.x), bhi(k.x), s);
    s = fmaf(blo(q.y), blo(k.y), s); s = fmaf(bhi(q.y), bhi(k.y), s);
    s = fmaf(blo(q.z), blo(k.z), s); s = fmaf(bhi(q.z), bhi(k.z), s);
    s = fmaf(blo(q.w), blo(k.w), s); s = fmaf(bhi(q.w), bhi(k.w), s);
    return s;
}

__device__ __forceinline__ void async16(void* lds, const void* g) {
    __builtin_amdgcn_global_load_lds((__attribute__((address_space(1))) void*)(void*)g,
                                     (__attribute__((address_space(3))) void*)(void*)lds,
                                     16, 0, 0);
}

// ---------------- transpose + cast f32[R][C] -> bf16[C][R] ----------------
__global__ __launch_bounds__(256) void tcast_k(const float* __restrict__ src,
                                               unsigned short* __restrict__ dst,
                                               int R, int C) {
    __shared__ float t[32][33];
    int c0 = blockIdx.x * 32, r0 = blockIdx.y * 32;
    int tx = threadIdx.x, ty = threadIdx.y;
#pragma unroll
    for (int k = 0; k < 32; k += 8)
        t[ty + k][tx] = src[(size_t)(r0 + ty + k) * C + c0 + tx];
    __syncthreads();
#pragma unroll
    for (int k = 0; k < 32; k += 8)
        dst[(size_t)(c0 + ty + k) * R + r0 + tx] = bfbits(t[tx][ty + k]);
}

// ---------------- pos-encoding table + qkv bias concat ----------------
__global__ __launch_bounds__(256) void prep_k(const float* __restrict__ bq,
                                              const float* __restrict__ bk,
                                              const float* __restrict__ bv,
                                              float* __restrict__ bias_qkv,
                                              float* __restrict__ pe) {
    int tid = blockIdx.x * 256 + threadIdx.x;
    if (tid < SEQ * DM) {
        int s = tid >> 9, c = tid & 511;
        int p = c >> 1;
        float div = expf(-(float)(2 * p) * (9.210340371976184f / 512.0f)); // ln(10000)/512
        float ang = (float)s * div;
        pe[tid] = (c & 1) ? cosf(ang) : sinf(ang);
    }
    if (tid < NL * 3 * DM) {
        int l = tid / (3 * DM), r = tid % (3 * DM);
        float v = (r < DM) ? bq[l * DM + r]
                : (r < 2 * DM) ? bk[l * DM + r - DM]
                               : bv[l * DM + r - 2 * DM];
        bias_qkv[tid] = v;
    }
}

// ---------------- cast x (f32) -> bf16 ----------------
__global__ __launch_bounds__(256) void xcast_k(const float* __restrict__ x,
                                               unsigned short* __restrict__ xb, int n) {
    int i = (blockIdx.x * 256 + threadIdx.x) * 4;
    if (i < n) {
        float4 v = *(const float4*)&x[i];
        uint2 o; o.x = pack2(v.x, v.y); o.y = pack2(v.z, v.w);
        *(uint2*)&xb[i] = o;
    }
}

// ---------------- bf16 MFMA GEMM: C[M,N] = A[M,K] @ Wt[N,K]^T + bias ----------------
// MODE 0: f32 out (+bias)      1: bf16 out (+bias)
// MODE 2: bf16 out relu(+bias) 3: embed: f32 + bf16 out (+bias +posenc)
template <int MODE>
__global__ __launch_bounds__(256) void gemm_k(const unsigned short* __restrict__ A,
                                              const unsigned short* __restrict__ Wt,
                                              const float* __restrict__ bias,
                                              float* __restrict__ outF,
                                              unsigned short* __restrict__ outB,
                                              const float* __restrict__ pe,
                                              int M, int N, int K) {
    __shared__ unsigned short As[128 * 32];
    __shared__ unsigned short Bs[128 * 32];
    const int tid = threadIdx.x;
    const int lane = tid & 63, wid = tid >> 6;
    const int wr = wid >> 1, wc = wid & 1;
    const int m0 = blockIdx.x * 128, n0 = blockIdx.y * 128;
    const int lr = lane & 15, kg = (lane >> 4) * 8;

    f32x4 acc[4][4] = {};

    for (int k0 = 0; k0 < K; k0 += 32) {
#pragma unroll
        for (int r = 0; r < 2; ++r) {
            int chunk = r * 256 + tid;          // 0..511
            int row = chunk >> 2;               // 0..127
            int kc  = (chunk & 3) << 3;         // 0,8,16,24
            async16(&As[chunk * 8], A  + (size_t)(m0 + row) * K + k0 + kc);
            async16(&Bs[chunk * 8], Wt + (size_t)(n0 + row) * K + k0 + kc);
        }
        __syncthreads();
        bf16x8 af[4], bf[4];
#pragma unroll
        for (int f = 0; f < 4; ++f) {
            af[f] = *(const bf16x8*)&As[(wr * 64 + f * 16 + lr) * 32 + kg];
            bf[f] = *(const bf16x8*)&Bs[(wc * 64 + f * 16 + lr) * 32 + kg];
        }
#pragma unroll
        for (int i = 0; i < 4; ++i)
#pragma unroll
            for (int j = 0; j < 4; ++j)
                acc[i][j] = __builtin_amdgcn_mfma_f32_16x16x32_bf16(af[i], bf[j], acc[i][j], 0, 0, 0);
        __syncthreads();
    }

#pragma unroll
    for (int i = 0; i < 4; ++i) {
#pragma unroll
        for (int j = 0; j < 4; ++j) {
            int col = n0 + wc * 64 + j * 16 + lr;
            float bv = bias[col];
#pragma unroll
            for (int v = 0; v < 4; ++v) {
                int row = m0 + wr * 64 + i * 16 + (lane >> 4) * 4 + v;
                float val = acc[i][j][v] + bv;
                size_t idx = (size_t)row * N + col;
                if (MODE == 0) {
                    outF[idx] = val;
                } else if (MODE == 1) {
                    outB[idx] = bfbits(val);
                } else if (MODE == 2) {
                    outB[idx] = bfbits(fmaxf(val, 0.f));
                } else {
                    float t = val + pe[(size_t)(row >> 5) * DM + col];
                    outF[idx] = t;
                    outB[idx] = bfbits(t);
                }
            }
        }
    }
}

// ---------------- sliding-window attention ----------------
// block: 256 thr (4 waves), 32 queries of one (b,h); wave handles 8 queries.
#define QBLK 32
#define NIB  16                 // ceil(500/32)
#define MAXK 131                // 99 + 32

__global__ __launch_bounds__(256) void attn_k(const unsigned short* __restrict__ qkv,
                                              unsigned short* __restrict__ ob) {
    __shared__ unsigned short Kl[MAXK][72];
    __shared__ unsigned short Ql[QBLK][72];
    __shared__ float Vl[MAXK][68];
    __shared__ float Pl[4][128];

    const int ib = blockIdx.x & (NIB - 1), bh = blockIdx.x >> 4;
    const int b = bh >> 3, h = bh & 7;
    const int i0 = ib * QBLK;
    const int jbase = max(0, i0 - (WINSZ - 1));
    const int jend = min(SEQ - 1, i0 + QBLK - 1);
    const int nkeys = jend - jbase + 1;
    const int tid = threadIdx.x;

    for (int idx = tid; idx < nkeys * 8; idx += 256) {
        int row = idx >> 3, c = (idx & 7) * 8;
        size_t grow = (size_t)((jbase + row) * BATCH + b) * (3 * DM) + h * HD + c;
        *(uint4*)&Kl[row][c] = *(const uint4*)&qkv[grow + DM];
        uint4 vw = *(const uint4*)&qkv[grow + 2 * DM];
        float4 v0 = {blo(vw.x), bhi(vw.x), blo(vw.y), bhi(vw.y)};
        float4 v1 = {blo(vw.z), bhi(vw.z), blo(vw.w), bhi(vw.w)};
        *(float4*)&Vl[row][c] = v0;
        *(float4*)&Vl[row][c + 4] = v1;
    }
    for (int idx = tid; idx < QBLK * 8; idx += 256) {
        int row = idx >> 3, c = (idx & 7) * 8;
        if (i0 + row < SEQ)
            *(uint4*)&Ql[row][c] =
                *(const uint4*)&qkv[(size_t)((i0 + row) * BATCH + b) * (3 * DM) + h * HD + c];
    }
    __syncthreads();

    const int lane = tid & 63, wid = tid >> 6;
    for (int t = 0; t < 8; ++t) {
        int qi = wid * 8 + t;
        int i = i0 + qi;
        if (i >= SEQ) break;                       // wave-uniform
        int jlo = max(0, i - (WINSZ - 1));
        int nk = i - jlo + 1;                      // <= 100
        int lb = jlo - jbase;
        bool val0 = lane < nk, val1 = lane + 64 < nk;
        int r0 = val0 ? lb + lane : lb;
        int r1 = val1 ? lb + lane + 64 : lb;
        float s0 = 0.f, s1 = 0.f;
#pragma unroll
        for (int c = 0; c < 8; ++c) {
            uint4 qw = *(const uint4*)&Ql[qi][c * 8];
            uint4 k0 = *(const uint4*)&Kl[r0][c * 8];
            uint4 k1 = *(const uint4*)&Kl[r1][c * 8];
            s0 = dot8(qw, k0, s0);
            s1 = dot8(qw, k1, s1);
        }
        s0 = val0 ? s0 * 0.125f : -1e30f;
        s1 = val1 ? s1 * 0.125f : -1e30f;
        float m = fmaxf(s0, s1);
#pragma unroll
        for (int off = 32; off; off >>= 1) m = fmaxf(m, __shfl_xor(m, off));
        float p0 = __expf(s0 - m), p1 = __expf(s1 - m);
        float sum = p0 + p1;
#pragma unroll
        for (int off = 32; off; off >>= 1) sum += __shfl_xor(sum, off);

        Pl[wid][lane] = p0;
        Pl[wid][64 + lane] = p1;
        asm volatile("" ::: "memory");             // same-wave LDS ordering

        float o = 0.f;
        int j4 = 0;
        for (; j4 + 4 <= nk; j4 += 4) {
            float4 pw = *(const float4*)&Pl[wid][j4];
            o = fmaf(pw.x, Vl[lb + j4 + 0][lane], o);
            o = fmaf(pw.y, Vl[lb + j4 + 1][lane], o);
            o = fmaf(pw.z, Vl[lb + j4 + 2][lane], o);
            o = fmaf(pw.w, Vl[lb + j4 + 3][lane], o);
        }
        for (int j = j4; j < nk; ++j)
            o = fmaf(Pl[wid][j], Vl[lb + j][lane], o);

        ob[(size_t)(i * BATCH + b) * DM + h * HD + lane] = bfbits(o / sum);
    }
}

// ---------------- residual + layernorm (wave per row) ----------------
__global__ __launch_bounds__(256) void ln_k(const float* __restrict__ hin,
                                            const float* __restrict__ yin,
                                            const float* __restrict__ sc,
                                            const float* __restrict__ bi,
                                            float* __restrict__ hout,
                                            unsigned short* __restrict__ hb) {
    int row = blockIdx.x * 4 + (threadIdx.x >> 6);
    int lane = threadIdx.x & 63;
    size_t base = (size_t)row * DM + lane * 8;
    float4 a0 = *(const float4*)&hin[base], a1 = *(const float4*)&hin[base + 4];
    float4 y0 = *(const float4*)&yin[base], y1 = *(const float4*)&yin[base + 4];
    float x[8] = {a0.x + y0.x, a0.y + y0.y, a0.z + y0.z, a0.w + y0.w,
                  a1.x + y1.x, a1.y + y1.y, a1.z + y1.z, a1.w + y1.w};
    float s = 0.f;
#pragma unroll
    for (int k = 0; k < 8; ++k) s += x[k];
#pragma unroll
    for (int off = 32; off; off >>= 1) s += __shfl_xor(s, off);
    float mean = s * (1.f / DM);
    float q = 0.f;
#pragma unroll
    for (int k = 0; k < 8; ++k) { float d = x[k] - mean; q = fmaf(d, d, q); }
#pragma unroll
    for (int off = 32; off; off >>= 1) q += __shfl_xor(q, off);
    float rstd = rsqrtf(q * (1.f / DM) + 1e-5f);
    float4 s0 = *(const float4*)&sc[lane * 8], s1 = *(const float4*)&sc[lane * 8 + 4];
    float4 b0 = *(const float4*)&bi[lane * 8], b1 = *(const float4*)&bi[lane * 8 + 4];
    float o[8];
    o[0] = (x[0] - mean) * rstd * s0.x + b0.x;  o[1] = (x[1] - mean) * rstd * s0.y + b0.y;
    o[2] = (x[2] - mean) * rstd * s0.z + b0.z;  o[3] = (x[3] - mean) * rstd * s0.w + b0.w;
    o[4] = (x[4] - mean) * rstd * s1.x + b1.x;  o[5] = (x[5] - mean) * rstd * s1.y + b1.y;
    o[6] = (x[6] - mean) * rstd * s1.z + b1.z;  o[7] = (x[7] - mean) * rstd * s1.w + b1.w;
    float4 w0 = {o[0], o[1], o[2], o[3]}, w1 = {o[4], o[5], o[6], o[7]};
    *(float4*)&hout[base] = w0;
    *(float4*)&hout[base + 4] = w1;
    uint4 pk = {pack2(o[0], o[1]), pack2(o[2], o[3]), pack2(o[4], o[5]), pack2(o[6], o[7])};
    *(uint4*)&hb[base] = pk;
}

// ---------------- host launch ----------------
extern "C" void kernel_launch(void* const* d_in, const int* in_sizes, int n_in,
                              void* d_out, int out_size, void* d_ws, size_t ws_size,
                              hipStream_t stream) {
    const float* x     = (const float*)d_in[0];
    const float* Wemb  = (const float*)d_in[1];
    const float* bemb  = (const float*)d_in[2];
    const float* Wq    = (const float*)d_in[3];
    const float* bq    = (const float*)d_in[4];
    const float* Wk    = (const float*)d_in[5];
    const float* bk    = (const float*)d_in[6];
    const float* Wv    = (const float*)d_in[7];
    const float* bv    = (const float*)d_in[8];
    const float* Wo    = (const float*)d_in[9];
    const float* bo    = (const float*)d_in[10];
    const float* ln1s  = (const float*)d_in[11];
    const float* ln1b  = (const float*)d_in[12];
    const float* W1    = (const float*)d_in[13];
    const float* b1    = (const float*)d_in[14];
    const float* W2    = (const float*)d_in[15];
    const float* b2    = (const float*)d_in[16];
    const float* ln2s  = (const float*)d_in[17];
    const float* ln2b  = (const float*)d_in[18];

    char* p = (char*)d_ws;
    auto carve = [&](size_t bytes) { char* r = p; p += (bytes + 255) & ~(size_t)255; return r; };

    unsigned short* wt_emb = (unsigned short*)carve((size_t)DM * DIN * 2);
    unsigned short* wt_qkv = (unsigned short*)carve((size_t)NL * 3 * DM * DM * 2);
    unsigned short* wt_o   = (unsigned short*)carve((size_t)NL * DM * DM * 2);
    unsigned short* wt_1   = (unsigned short*)carve((size_t)NL * DF * DM * 2);
    unsigned short* wt_2   = (unsigned short*)carve((size_t)NL * DM * DF * 2);
    float*          biasq  = (float*)carve((size_t)NL * 3 * DM * 4);
    float*          pe     = (float*)carve((size_t)SEQ * DM * 4);
    unsigned short* xb     = (unsigned short*)carve((size_t)ROWS * DIN * 2);
    float*          h      = (float*)carve((size_t)ROWS * DM * 4);
    unsigned short* hb     = (unsigned short*)carve((size_t)ROWS * DM * 2);
    unsigned short* ob     = (unsigned short*)carve((size_t)ROWS * DM * 2);
    float*          t0     = (float*)carve((size_t)ROWS * DM * 4);
    unsigned short* qkv    = (unsigned short*)carve((size_t)ROWS * DF * 2); // aliased: qkv (x1536) / f1 (x2048)
    unsigned short* f1     = qkv;

    dim3 blk256(256);

    // weight transposes
    tcast_k<<<dim3(DM / 32, DIN / 32), dim3(32, 8), 0, stream>>>(Wemb, wt_emb, DIN, DM);
    for (int l = 0; l < NL; ++l) {
        tcast_k<<<dim3(DM / 32, DM / 32), dim3(32, 8), 0, stream>>>(Wq + (size_t)l * DM * DM, wt_qkv + (size_t)l * 3 * DM * DM, DM, DM);
        tcast_k<<<dim3(DM / 32, DM / 32), dim3(32, 8), 0, stream>>>(Wk + (size_t)l * DM * DM, wt_qkv + (size_t)l * 3 * DM * DM + (size_t)DM * DM, DM, DM);
        tcast_k<<<dim3(DM / 32, DM / 32), dim3(32, 8), 0, stream>>>(Wv + (size_t)l * DM * DM, wt_qkv + (size_t)l * 3 * DM * DM + (size_t)2 * DM * DM, DM, DM);
        tcast_k<<<dim3(DM / 32, DM / 32), dim3(32, 8), 0, stream>>>(Wo + (size_t)l * DM * DM, wt_o + (size_t)l * DM * DM, DM, DM);
        tcast_k<<<dim3(DF / 32, DM / 32), dim3(32, 8), 0, stream>>>(W1 + (size_t)l * DM * DF, wt_1 + (size_t)l * DF * DM, DM, DF);
        tcast_k<<<dim3(DM / 32, DF / 32), dim3(32, 8), 0, stream>>>(W2 + (size_t)l * DF * DM, wt_2 + (size_t)l * DM * DF, DF, DM);
    }
    prep_k<<<dim3((SEQ * DM + 255) / 256), blk256, 0, stream>>>(bq, bk, bv, biasq, pe);
    xcast_k<<<dim3(ROWS * DIN / 4 / 256), blk256, 0, stream>>>(x, xb, ROWS * DIN);

    // embedding + posenc
    gemm_k<3><<<dim3(ROWS / 128, DM / 128), blk256, 0, stream>>>(xb, wt_emb, bemb, h, hb, pe, ROWS, DM, DIN);

    for (int l = 0; l < NL; ++l) {
        // QKV
        gemm_k<1><<<dim3(ROWS / 128, 3 * DM / 128), blk256, 0, stream>>>(
            hb, wt_qkv + (size_t)l * 3 * DM * DM, biasq + (size_t)l * 3 * DM,
            nullptr, qkv, nullptr, ROWS, 3 * DM, DM);
        // attention
        attn_k<<<dim3(BATCH * NH * NIB), blk256, 0, stream>>>(qkv, ob);
        // O-proj -> t0
        gemm_k<0><<<dim3(ROWS / 128, DM / 128), blk256, 0, stream>>>(
            ob, wt_o + (size_t)l * DM * DM, bo + (size_t)l * DM,
            t0, nullptr, nullptr, ROWS, DM, DM);
        // LN1: h = LN(h + t0)
        ln_k<<<dim3(ROWS / 4), blk256, 0, stream>>>(h, t0, ln1s + (size_t)l * DM, ln1b + (size_t)l * DM, h, hb);
        // FFN1 -> f1 (relu, bf16)
        gemm_k<2><<<dim3(ROWS / 128, DF / 128), blk256, 0, stream>>>(
            hb, wt_1 + (size_t)l * DF * DM, b1 + (size_t)l * DF,
            nullptr, f1, nullptr, ROWS, DF, DM);
        // FFN2 -> t0
        gemm_k<0><<<dim3(ROWS / 128, DM / 128), blk256, 0, stream>>>(
            f1, wt_2 + (size_t)l * DM * DF, b2 + (size_t)l * DM,
            t0, nullptr, nullptr, ROWS, DM, DF);
        // LN2: h = LN(h + t0) ; final layer writes d_out
        float* hdst = (l == NL - 1) ? (float*)d_out : h;
        ln_k<<<dim3(ROWS / 4), blk256, 0, stream>>>(h, t0, ln2s + (size_t)l * DM, ln2b + (size_t)l * DM, hdst, hb);
    }
}

// Round 3
// 654.423 us; speedup vs baseline: 1.3922x; 1.3922x over previous
//
#include <hip/hip_runtime.h>
#include <stdint.h>

// ---------------- problem constants ----------------
#define SEQ   500
#define BATCH 32
#define DIN   256
#define DM    512
#define NH    8
#define NL    2
#define DF    2048
#define WINSZ 100
#define HD    64          // DM/NH
#define ROWS  (SEQ*BATCH) // 16000

typedef __bf16 bf16x8 __attribute__((ext_vector_type(8)));
typedef float  f32x4  __attribute__((ext_vector_type(4)));

// ---------------- helpers ----------------
__device__ __forceinline__ unsigned short bfbits(float f) {
    unsigned int u = __builtin_bit_cast(unsigned int, f);
    u = u + 0x7fffu + ((u >> 16) & 1u);           // RNE
    return (unsigned short)(u >> 16);
}
__device__ __forceinline__ unsigned int pack2(float a, float b) {
    return (unsigned int)bfbits(a) | ((unsigned int)bfbits(b) << 16);
}
__device__ __forceinline__ float blo(unsigned int u) { return __builtin_bit_cast(float, u << 16); }
__device__ __forceinline__ float bhi(unsigned int u) { return __builtin_bit_cast(float, u & 0xffff0000u); }

__device__ __forceinline__ void async16(void* lds, const void* g) {
    __builtin_amdgcn_global_load_lds((__attribute__((address_space(1))) void*)(void*)g,
                                     (__attribute__((address_space(3))) void*)(void*)lds,
                                     16, 0, 0);
}

// ---------------- transpose + cast f32[R][C] -> bf16[C][R] ----------------
__global__ __launch_bounds__(256) void tcast_k(const float* __restrict__ src,
                                               unsigned short* __restrict__ dst,
                                               int R, int C) {
    __shared__ float t[32][33];
    int c0 = blockIdx.x * 32, r0 = blockIdx.y * 32;
    int tx = threadIdx.x, ty = threadIdx.y;
#pragma unroll
    for (int k = 0; k < 32; k += 8)
        t[ty + k][tx] = src[(size_t)(r0 + ty + k) * C + c0 + tx];
    __syncthreads();
#pragma unroll
    for (int k = 0; k < 32; k += 8)
        dst[(size_t)(c0 + ty + k) * R + r0 + tx] = bfbits(t[tx][ty + k]);
}

// ---------------- pos-encoding table + qkv bias concat ----------------
__global__ __launch_bounds__(256) void prep_k(const float* __restrict__ bq,
                                              const float* __restrict__ bk,
                                              const float* __restrict__ bv,
                                              float* __restrict__ bias_qkv,
                                              float* __restrict__ pe) {
    int tid = blockIdx.x * 256 + threadIdx.x;
    if (tid < SEQ * DM) {
        int s = tid >> 9, c = tid & 511;
        int p = c >> 1;
        float div = expf(-(float)(2 * p) * (9.210340371976184f / 512.0f)); // ln(10000)/512
        float ang = (float)s * div;
        pe[tid] = (c & 1) ? cosf(ang) : sinf(ang);
    }
    if (tid < NL * 3 * DM) {
        int l = tid / (3 * DM), r = tid % (3 * DM);
        float v = (r < DM) ? bq[l * DM + r]
                : (r < 2 * DM) ? bk[l * DM + r - DM]
                               : bv[l * DM + r - 2 * DM];
        bias_qkv[tid] = v;
    }
}

// ---------------- cast x (f32) -> bf16 ----------------
__global__ __launch_bounds__(256) void xcast_k(const float* __restrict__ x,
                                               unsigned short* __restrict__ xb, int n) {
    int i = (blockIdx.x * 256 + threadIdx.x) * 4;
    if (i < n) {
        float4 v = *(const float4*)&x[i];
        uint2 o; o.x = pack2(v.x, v.y); o.y = pack2(v.z, v.w);
        *(uint2*)&xb[i] = o;
    }
}

// ---------------- bf16 MFMA GEMM: C[M,N] = A[M,K] @ Wt[N,K]^T + bias ----------------
// MODE 0: f32 out (+bias)      1: bf16 out (+bias)
// MODE 2: bf16 out relu(+bias) 3: embed: f32 + bf16 out (+bias +posenc)
template <int MODE>
__global__ __launch_bounds__(256) void gemm_k(const unsigned short* __restrict__ A,
                                              const unsigned short* __restrict__ Wt,
                                              const float* __restrict__ bias,
                                              float* __restrict__ outF,
                                              unsigned short* __restrict__ outB,
                                              const float* __restrict__ pe,
                                              int M, int N, int K) {
    __shared__ unsigned short As[128 * 32];
    __shared__ unsigned short Bs[128 * 32];
    const int tid = threadIdx.x;
    const int lane = tid & 63, wid = tid >> 6;
    const int wr = wid >> 1, wc = wid & 1;
    const int m0 = blockIdx.x * 128, n0 = blockIdx.y * 128;
    const int lr = lane & 15, kg = (lane >> 4) * 8;

    f32x4 acc[4][4] = {};

    for (int k0 = 0; k0 < K; k0 += 32) {
#pragma unroll
        for (int r = 0; r < 2; ++r) {
            int chunk = r * 256 + tid;          // 0..511
            int row = chunk >> 2;               // 0..127
            int kc  = (chunk & 3) << 3;         // 0,8,16,24
            async16(&As[chunk * 8], A  + (size_t)(m0 + row) * K + k0 + kc);
            async16(&Bs[chunk * 8], Wt + (size_t)(n0 + row) * K + k0 + kc);
        }
        __syncthreads();
        bf16x8 af[4], bf[4];
#pragma unroll
        for (int f = 0; f < 4; ++f) {
            af[f] = *(const bf16x8*)&As[(wr * 64 + f * 16 + lr) * 32 + kg];
            bf[f] = *(const bf16x8*)&Bs[(wc * 64 + f * 16 + lr) * 32 + kg];
        }
#pragma unroll
        for (int i = 0; i < 4; ++i)
#pragma unroll
            for (int j = 0; j < 4; ++j)
                acc[i][j] = __builtin_amdgcn_mfma_f32_16x16x32_bf16(af[i], bf[j], acc[i][j], 0, 0, 0);
        __syncthreads();
    }

#pragma unroll
    for (int i = 0; i < 4; ++i) {
#pragma unroll
        for (int j = 0; j < 4; ++j) {
            int col = n0 + wc * 64 + j * 16 + lr;
            float bv = bias[col];
#pragma unroll
            for (int v = 0; v < 4; ++v) {
                int row = m0 + wr * 64 + i * 16 + (lane >> 4) * 4 + v;
                float val = acc[i][j][v] + bv;
                size_t idx = (size_t)row * N + col;
                if (MODE == 0) {
                    outF[idx] = val;
                } else if (MODE == 1) {
                    outB[idx] = bfbits(val);
                } else if (MODE == 2) {
                    outB[idx] = bfbits(fmaxf(val, 0.f));
                } else {
                    float t = val + pe[(size_t)(row >> 5) * DM + col];
                    outF[idx] = t;
                    outB[idx] = bfbits(t);
                }
            }
        }
    }
}

// ---------------- V transpose: qkv V-part -> vT[bh][64][512] (bf16, zero-padded) ----
__global__ __launch_bounds__(256) void vtrans_k(const unsigned short* __restrict__ qkv,
                                                unsigned short* __restrict__ vT) {
    __shared__ unsigned short t[32][72];
    const int s0 = blockIdx.x * 32;
    const int bh = blockIdx.y;
    const int b = bh >> 3, h = bh & 7;
    const int tid = threadIdx.x;
    {
        int sl = tid >> 3;                 // 0..31
        int c  = tid & 7;                  // d-chunk
        int s  = s0 + sl;
        uint4 val = {0, 0, 0, 0};
        if (s < SEQ)
            val = *(const uint4*)&qkv[(size_t)(s * BATCH + b) * (3 * DM) + 2 * DM + h * HD + c * 8];
        *(uint4*)&t[sl][c * 8] = val;
    }
    __syncthreads();
    {
        int d  = tid >> 2;                 // 0..63
        int s8 = (tid & 3) * 8;            // 0,8,16,24
        unsigned short v[8];
#pragma unroll
        for (int j = 0; j < 8; ++j) v[j] = t[s8 + j][d];
        *(uint4*)&vT[(size_t)(bh * 64 + d) * 512 + s0 + s8] = *(uint4*)v;
    }
}

// ---------------- sliding-window attention, MFMA (plain-LDS version) ----------------
// Block: 128 thr (2 waves). 32 queries of one (b,h); wave w owns 16 queries.
// S^T = K @ Q^T via mfma (keys in rows, queries in cols) -> in-reg softmax
// -> P (bf16) to LDS -> O = P @ V via mfma; V fragments from pre-transposed vT.
#define QBLK  32
#define NIB   16                 // ceil(500/32)
#define KTIL  9                  // key tiles of 16 -> 144 rows
#define PKEYS 160                // 5 K-steps of 32
#define KSTR  72                 // Kl row stride (shorts)
#define VSTR  168                // Vt row stride (shorts)
#define PSTR  168                // Pl row stride (shorts)

__global__ __launch_bounds__(128) void attn_k(const unsigned short* __restrict__ qkv,
                                              const unsigned short* __restrict__ vT,
                                              unsigned short* __restrict__ ob) {
    __shared__ unsigned short Kl[KTIL * 16 * KSTR]; // 144x72  (20.25 KB)
    __shared__ unsigned short Vt[64 * VSTR];        // 64x168  (21 KB)
    __shared__ unsigned short Pl[QBLK * PSTR];      // 32x168  (10.5 KB)

    const int ib = blockIdx.x & (NIB - 1), bh = blockIdx.x >> 4;
    const int b = bh >> 3, h = bh & 7;
    const int i0 = ib * QBLK;
    const int jbase = max(0, i0 - (WINSZ - 1));
    const int jend  = min(SEQ - 1, i0 + QBLK - 1);
    const int nkeys = jend - jbase + 1;          // <= 131
    const int NT  = (nkeys + 15) >> 4;           // key tiles
    const int NKS = (nkeys + 31) >> 5;           // PV K-steps
    const int tid = threadIdx.x, lane = tid & 63, w = tid >> 6;
    const int q15 = lane & 15, grp = lane >> 4;

    // ---- stage K rows (zero-fill beyond nkeys): 144 rows x 8 chunks ----
#pragma unroll
    for (int it = 0; it < 9; ++it) {
        int g = it * 128 + tid;                  // 0..1151
        int row = g >> 3, c = g & 7;
        uint4 val = {0, 0, 0, 0};
        if (row < nkeys)
            val = *(const uint4*)&qkv[(size_t)((jbase + row) * BATCH + b) * (3 * DM)
                                      + DM + h * HD + c * 8];
        *(uint4*)&Kl[row * KSTR + c * 8] = val;
    }
    // ---- stage V^T rows from vT (zero-padded source): 64 rows x 20 chunks ----
#pragma unroll
    for (int it = 0; it < 10; ++it) {
        int g = it * 128 + tid;                  // 0..1279
        int r = g / 20, c = g - r * 20;
        uint4 val = {0, 0, 0, 0};
        if (jbase + c * 8 < SEQ)
            val = *(const uint4*)&vT[(size_t)(bh * 64 + r) * 512 + jbase + c * 8];
        *(uint4*)&Vt[r * VSTR + c * 8] = val;
    }
    // ---- zero P (tail K-steps multiply by exact zeros) ----
#pragma unroll
    for (int it = 0; it < 6; ++it) {
        int g = it * 128 + tid;                  // 672 granules = 32*168 shorts
        if (g < 672) { uint4 z = {0, 0, 0, 0}; *(uint4*)&Pl[g * 8] = z; }
    }
    // ---- Q direct to regs (B-fragments) ----
    bf16x8 qav, qbv;
    {
        int iq = min(i0 + w * 16 + q15, SEQ - 1);
        size_t qrow = (size_t)(iq * BATCH + b) * (3 * DM) + h * HD;
        uint4 a = *(const uint4*)&qkv[qrow + grp * 8];
        uint4 c = *(const uint4*)&qkv[qrow + 32 + grp * 8];
        qav = __builtin_bit_cast(bf16x8, a);
        qbv = __builtin_bit_cast(bf16x8, c);
    }
    __syncthreads();

    // ---- QK^T (S^T layout: row=key, col=query) + mask ----
    const int i = i0 + w * 16 + q15;             // this lane's query (as col)
    float sc[KTIL][4];
#pragma unroll
    for (int t = 0; t < KTIL; ++t) {
        if (t >= NT) continue;                   // uniform
        f32x4 acc = {};
        int row = t * 16 + q15;                  // key row (A-frag: lane&15)
        bf16x8 kf0 = *(const bf16x8*)&Kl[row * KSTR + grp * 8];
        acc = __builtin_amdgcn_mfma_f32_16x16x32_bf16(kf0, qav, acc, 0, 0, 0);
        bf16x8 kf1 = *(const bf16x8*)&Kl[row * KSTR + 32 + grp * 8];
        acc = __builtin_amdgcn_mfma_f32_16x16x32_bf16(kf1, qbv, acc, 0, 0, 0);
#pragma unroll
        for (int v = 0; v < 4; ++v) {
            int key = jbase + t * 16 + grp * 4 + v;   // C-layout row
            bool valid = (key <= i) && (key > i - WINSZ);
            sc[t][v] = valid ? acc[v] * 0.125f : -1e30f;
        }
    }
    // ---- softmax over keys (local 36 + xor16 + xor32: lanes {q15,+16,+32,+48}) ----
    float m = -1e30f;
#pragma unroll
    for (int t = 0; t < KTIL; ++t) {
        if (t >= NT) continue;
#pragma unroll
        for (int v = 0; v < 4; ++v) m = fmaxf(m, sc[t][v]);
    }
    m = fmaxf(m, __shfl_xor(m, 16));
    m = fmaxf(m, __shfl_xor(m, 32));
    float sum = 0.f;
#pragma unroll
    for (int t = 0; t < KTIL; ++t) {
        if (t >= NT) continue;
#pragma unroll
        for (int v = 0; v < 4; ++v) {
            float p = __expf(sc[t][v] - m);
            sc[t][v] = p;
            sum += p;
        }
    }
    sum += __shfl_xor(sum, 16);
    sum += __shfl_xor(sum, 32);
    // ---- P -> LDS (bf16; row = query, col = key) ----
#pragma unroll
    for (int t = 0; t < KTIL; ++t) {
        if (t >= NT) continue;
        uint2 pk;
        pk.x = pack2(sc[t][0], sc[t][1]);
        pk.y = pack2(sc[t][2], sc[t][3]);
        *(uint2*)&Pl[(w * 16 + q15) * PSTR + t * 16 + grp * 4] = pk;
    }
    // (no barrier: each wave reads only its own P rows)

    // ---- PV: O = P @ V ; A-frag = P rows, B-frag = Vt rows (GEMM-style) ----
    f32x4 oacc[4] = {};
#pragma unroll
    for (int ks = 0; ks < 5; ++ks) {
        if (ks >= NKS) continue;                 // uniform
        bf16x8 pf = *(const bf16x8*)&Pl[(w * 16 + q15) * PSTR + ks * 32 + grp * 8];
#pragma unroll
        for (int dt = 0; dt < 4; ++dt) {
            bf16x8 vf = *(const bf16x8*)&Vt[(dt * 16 + q15) * VSTR + ks * 32 + grp * 8];
            oacc[dt] = __builtin_amdgcn_mfma_f32_16x16x32_bf16(pf, vf, oacc[dt], 0, 0, 0);
        }
    }

    // ---- normalize + store (C row = grp*4+v = query; col = q15 = d) ----
#pragma unroll
    for (int v = 0; v < 4; ++v) {
        float rsv = 1.0f / __shfl(sum, grp * 4 + v);
        int irow = i0 + w * 16 + grp * 4 + v;
        if (irow < SEQ) {
            size_t base = (size_t)(irow * BATCH + b) * DM + h * HD + q15;
#pragma unroll
            for (int dt = 0; dt < 4; ++dt)
                ob[base + dt * 16] = bfbits(oacc[dt][v] * rsv);
        }
    }
}

// ---------------- residual + layernorm (wave per row) ----------------
__global__ __launch_bounds__(256) void ln_k(const float* __restrict__ hin,
                                            const float* __restrict__ yin,
                                            const float* __restrict__ sc,
                                            const float* __restrict__ bi,
                                            float* __restrict__ hout,
                                            unsigned short* __restrict__ hb) {
    int row = blockIdx.x * 4 + (threadIdx.x >> 6);
    int lane = threadIdx.x & 63;
    size_t base = (size_t)row * DM + lane * 8;
    float4 a0 = *(const float4*)&hin[base], a1 = *(const float4*)&hin[base + 4];
    float4 y0 = *(const float4*)&yin[base], y1 = *(const float4*)&yin[base + 4];
    float x[8] = {a0.x + y0.x, a0.y + y0.y, a0.z + y0.z, a0.w + y0.w,
                  a1.x + y1.x, a1.y + y1.y, a1.z + y1.z, a1.w + y1.w};
    float s = 0.f;
#pragma unroll
    for (int k = 0; k < 8; ++k) s += x[k];
#pragma unroll
    for (int off = 32; off; off >>= 1) s += __shfl_xor(s, off);
    float mean = s * (1.f / DM);
    float q = 0.f;
#pragma unroll
    for (int k = 0; k < 8; ++k) { float d = x[k] - mean; q = fmaf(d, d, q); }
#pragma unroll
    for (int off = 32; off; off >>= 1) q += __shfl_xor(q, off);
    float rstd = rsqrtf(q * (1.f / DM) + 1e-5f);
    float4 s0 = *(const float4*)&sc[lane * 8], s1 = *(const float4*)&sc[lane * 8 + 4];
    float4 b0 = *(const float4*)&bi[lane * 8], b1 = *(const float4*)&bi[lane * 8 + 4];
    float o[8];
    o[0] = (x[0] - mean) * rstd * s0.x + b0.x;  o[1] = (x[1] - mean) * rstd * s0.y + b0.y;
    o[2] = (x[2] - mean) * rstd * s0.z + b0.z;  o[3] = (x[3] - mean) * rstd * s0.w + b0.w;
    o[4] = (x[4] - mean) * rstd * s1.x + b1.x;  o[5] = (x[5] - mean) * rstd * s1.y + b1.y;
    o[6] = (x[6] - mean) * rstd * s1.z + b1.z;  o[7] = (x[7] - mean) * rstd * s1.w + b1.w;
    float4 w0 = {o[0], o[1], o[2], o[3]}, w1 = {o[4], o[5], o[6], o[7]};
    *(float4*)&hout[base] = w0;
    *(float4*)&hout[base + 4] = w1;
    uint4 pk = {pack2(o[0], o[1]), pack2(o[2], o[3]), pack2(o[4], o[5]), pack2(o[6], o[7])};
    *(uint4*)&hb[base] = pk;
}

// ---------------- host launch ----------------
extern "C" void kernel_launch(void* const* d_in, const int* in_sizes, int n_in,
                              void* d_out, int out_size, void* d_ws, size_t ws_size,
                              hipStream_t stream) {
    const float* x     = (const float*)d_in[0];
    const float* Wemb  = (const float*)d_in[1];
    const float* bemb  = (const float*)d_in[2];
    const float* Wq    = (const float*)d_in[3];
    const float* bq    = (const float*)d_in[4];
    const float* Wk    = (const float*)d_in[5];
    const float* bk    = (const float*)d_in[6];
    const float* Wv    = (const float*)d_in[7];
    const float* bv    = (const float*)d_in[8];
    const float* Wo    = (const float*)d_in[9];
    const float* bo    = (const float*)d_in[10];
    const float* ln1s  = (const float*)d_in[11];
    const float* ln1b  = (const float*)d_in[12];
    const float* W1    = (const float*)d_in[13];
    const float* b1    = (const float*)d_in[14];
    const float* W2    = (const float*)d_in[15];
    const float* b2    = (const float*)d_in[16];
    const float* ln2s  = (const float*)d_in[17];
    const float* ln2b  = (const float*)d_in[18];

    char* p = (char*)d_ws;
    auto carve = [&](size_t bytes) { char* r = p; p += (bytes + 255) & ~(size_t)255; return r; };

    unsigned short* wt_emb = (unsigned short*)carve((size_t)DM * DIN * 2);
    unsigned short* wt_qkv = (unsigned short*)carve((size_t)NL * 3 * DM * DM * 2);
    unsigned short* wt_o   = (unsigned short*)carve((size_t)NL * DM * DM * 2);
    unsigned short* wt_1   = (unsigned short*)carve((size_t)NL * DF * DM * 2);
    unsigned short* wt_2   = (unsigned short*)carve((size_t)NL * DM * DF * 2);
    float*          biasq  = (float*)carve((size_t)NL * 3 * DM * 4);
    float*          pe     = (float*)carve((size_t)SEQ * DM * 4);
    unsigned short* xb     = (unsigned short*)carve((size_t)ROWS * DIN * 2);
    float*          h      = (float*)carve((size_t)ROWS * DM * 4);
    unsigned short* hb     = (unsigned short*)carve((size_t)ROWS * DM * 2);
    unsigned short* ob     = (unsigned short*)carve((size_t)ROWS * DM * 2);
    float*          t0     = (float*)carve((size_t)ROWS * DM * 4);
    unsigned short* vT     = (unsigned short*)carve((size_t)BATCH * NH * 64 * 512 * 2 + 1024);
    unsigned short* qkv    = (unsigned short*)carve((size_t)ROWS * DF * 2); // aliased: qkv (x1536) / f1 (x2048)
    unsigned short* f1     = qkv;

    dim3 blk256(256);

    // weight transposes
    tcast_k<<<dim3(DM / 32, DIN / 32), dim3(32, 8), 0, stream>>>(Wemb, wt_emb, DIN, DM);
    for (int l = 0; l < NL; ++l) {
        tcast_k<<<dim3(DM / 32, DM / 32), dim3(32, 8), 0, stream>>>(Wq + (size_t)l * DM * DM, wt_qkv + (size_t)l * 3 * DM * DM, DM, DM);
        tcast_k<<<dim3(DM / 32, DM / 32), dim3(32, 8), 0, stream>>>(Wk + (size_t)l * DM * DM, wt_qkv + (size_t)l * 3 * DM * DM + (size_t)DM * DM, DM, DM);
        tcast_k<<<dim3(DM / 32, DM / 32), dim3(32, 8), 0, stream>>>(Wv + (size_t)l * DM * DM, wt_qkv + (size_t)l * 3 * DM * DM + (size_t)2 * DM * DM, DM, DM);
        tcast_k<<<dim3(DM / 32, DM / 32), dim3(32, 8), 0, stream>>>(Wo + (size_t)l * DM * DM, wt_o + (size_t)l * DM * DM, DM, DM);
        tcast_k<<<dim3(DF / 32, DM / 32), dim3(32, 8), 0, stream>>>(W1 + (size_t)l * DM * DF, wt_1 + (size_t)l * DF * DM, DM, DF);
        tcast_k<<<dim3(DM / 32, DF / 32), dim3(32, 8), 0, stream>>>(W2 + (size_t)l * DF * DM, wt_2 + (size_t)l * DM * DF, DF, DM);
    }
    prep_k<<<dim3((SEQ * DM + 255) / 256), blk256, 0, stream>>>(bq, bk, bv, biasq, pe);
    xcast_k<<<dim3(ROWS * DIN / 4 / 256), blk256, 0, stream>>>(x, xb, ROWS * DIN);

    // embedding + posenc
    gemm_k<3><<<dim3(ROWS / 128, DM / 128), blk256, 0, stream>>>(xb, wt_emb, bemb, h, hb, pe, ROWS, DM, DIN);

    for (int l = 0; l < NL; ++l) {
        // QKV
        gemm_k<1><<<dim3(ROWS / 128, 3 * DM / 128), blk256, 0, stream>>>(
            hb, wt_qkv + (size_t)l * 3 * DM * DM, biasq + (size_t)l * 3 * DM,
            nullptr, qkv, nullptr, ROWS, 3 * DM, DM);
        // V transpose -> vT[bh][64][512] (zero-padded)
        vtrans_k<<<dim3(16, BATCH * NH), blk256, 0, stream>>>(qkv, vT);
        // attention (MFMA)
        attn_k<<<dim3(BATCH * NH * NIB), dim3(128), 0, stream>>>(qkv, vT, ob);
        // O-proj -> t0
        gemm_k<0><<<dim3(ROWS / 128, DM / 128), blk256, 0, stream>>>(
            ob, wt_o + (size_t)l * DM * DM, bo + (size_t)l * DM,
            t0, nullptr, nullptr, ROWS, DM, DM);
        // LN1: h = LN(h + t0)
        ln_k<<<dim3(ROWS / 4), blk256, 0, stream>>>(h, t0, ln1s + (size_t)l * DM, ln1b + (size_t)l * DM, h, hb);
        // FFN1 -> f1 (relu, bf16)
        gemm_k<2><<<dim3(ROWS / 128, DF / 128), blk256, 0, stream>>>(
            hb, wt_1 + (size_t)l * DF * DM, b1 + (size_t)l * DF,
            nullptr, f1, nullptr, ROWS, DF, DM);
        // FFN2 -> t0
        gemm_k<0><<<dim3(ROWS / 128, DM / 128), blk256, 0, stream>>>(
            f1, wt_2 + (size_t)l * DM * DF, b2 + (size_t)l * DM,
            t0, nullptr, nullptr, ROWS, DM, DF);
        // LN2: h = LN(h + t0) ; final layer writes d_out
        float* hdst = (l == NL - 1) ? (float*)d_out : h;
        ln_k<<<dim3(ROWS / 4), blk256, 0, stream>>>(h, t0, ln2s + (size_t)l * DM, ln2b + (size_t)l * DM, hdst, hb);
    }
}

// Round 4
// 574.143 us; speedup vs baseline: 1.5869x; 1.1398x over previous
//
#include <hip/hip_runtime.h>
#include <stdint.h>

// ---------------- problem constants ----------------
#define SEQ   500
#define BATCH 32
#define DIN   256
#define DM    512
#define NH    8
#define NL    2
#define DF    2048
#define WINSZ 100
#define HD    64          // DM/NH
#define ROWS  (SEQ*BATCH) // 16000

typedef __bf16 bf16x8 __attribute__((ext_vector_type(8)));
typedef float  f32x4  __attribute__((ext_vector_type(4)));

// ---------------- helpers ----------------
__device__ __forceinline__ unsigned short bfbits(float f) {
    unsigned int u = __builtin_bit_cast(unsigned int, f);
    u = u + 0x7fffu + ((u >> 16) & 1u);           // RNE
    return (unsigned short)(u >> 16);
}
__device__ __forceinline__ unsigned int pack2(float a, float b) {
    return (unsigned int)bfbits(a) | ((unsigned int)bfbits(b) << 16);
}
__device__ __forceinline__ float blo(unsigned int u) { return __builtin_bit_cast(float, u << 16); }
__device__ __forceinline__ float bhi(unsigned int u) { return __builtin_bit_cast(float, u & 0xffff0000u); }

__device__ __forceinline__ void async16(void* lds, const void* g) {
    __builtin_amdgcn_global_load_lds((__attribute__((address_space(1))) void*)(void*)g,
                                     (__attribute__((address_space(3))) void*)(void*)lds,
                                     16, 0, 0);
}

// ---------------- transpose + cast f32[R][C] -> bf16[C][R] ----------------
__global__ __launch_bounds__(256) void tcast_k(const float* __restrict__ src,
                                               unsigned short* __restrict__ dst,
                                               int R, int C) {
    __shared__ float t[32][33];
    int c0 = blockIdx.x * 32, r0 = blockIdx.y * 32;
    int tx = threadIdx.x, ty = threadIdx.y;
#pragma unroll
    for (int k = 0; k < 32; k += 8)
        t[ty + k][tx] = src[(size_t)(r0 + ty + k) * C + c0 + tx];
    __syncthreads();
#pragma unroll
    for (int k = 0; k < 32; k += 8)
        dst[(size_t)(c0 + ty + k) * R + r0 + tx] = bfbits(t[tx][ty + k]);
}

// ---------------- pos-encoding table + qkv bias concat ----------------
__global__ __launch_bounds__(256) void prep_k(const float* __restrict__ bq,
                                              const float* __restrict__ bk,
                                              const float* __restrict__ bv,
                                              float* __restrict__ bias_qkv,
                                              float* __restrict__ pe) {
    int tid = blockIdx.x * 256 + threadIdx.x;
    if (tid < SEQ * DM) {
        int s = tid >> 9, c = tid & 511;
        int p = c >> 1;
        float div = expf(-(float)(2 * p) * (9.210340371976184f / 512.0f)); // ln(10000)/512
        float ang = (float)s * div;
        pe[tid] = (c & 1) ? cosf(ang) : sinf(ang);
    }
    if (tid < NL * 3 * DM) {
        int l = tid / (3 * DM), r = tid % (3 * DM);
        float v = (r < DM) ? bq[l * DM + r]
                : (r < 2 * DM) ? bk[l * DM + r - DM]
                               : bv[l * DM + r - 2 * DM];
        bias_qkv[tid] = v;
    }
}

// ---------------- cast x (f32) -> bf16 ----------------
__global__ __launch_bounds__(256) void xcast_k(const float* __restrict__ x,
                                               unsigned short* __restrict__ xb, int n) {
    int i = (blockIdx.x * 256 + threadIdx.x) * 4;
    if (i < n) {
        float4 v = *(const float4*)&x[i];
        uint2 o; o.x = pack2(v.x, v.y); o.y = pack2(v.z, v.w);
        *(uint2*)&xb[i] = o;
    }
}

// ---------------- bf16 MFMA GEMM: C[M,N] = A[M,K] @ Wt[N,K]^T + bias ----------------
// MODE 0: f32 out (+bias)      1: bf16 out (+bias)
// MODE 2: bf16 out relu(+bias) 3: embed: f32 + bf16 out (+bias +posenc)
template <int MODE>
__global__ __launch_bounds__(256) void gemm_k(const unsigned short* __restrict__ A,
                                              const unsigned short* __restrict__ Wt,
                                              const float* __restrict__ bias,
                                              float* __restrict__ outF,
                                              unsigned short* __restrict__ outB,
                                              const float* __restrict__ pe,
                                              int M, int N, int K) {
    __shared__ unsigned short As[128 * 32];
    __shared__ unsigned short Bs[128 * 32];
    const int tid = threadIdx.x;
    const int lane = tid & 63, wid = tid >> 6;
    const int wr = wid >> 1, wc = wid & 1;
    const int m0 = blockIdx.x * 128, n0 = blockIdx.y * 128;
    const int lr = lane & 15, kg = (lane >> 4) * 8;

    f32x4 acc[4][4] = {};

    for (int k0 = 0; k0 < K; k0 += 32) {
#pragma unroll
        for (int r = 0; r < 2; ++r) {
            int chunk = r * 256 + tid;          // 0..511
            int row = chunk >> 2;               // 0..127
            int kc  = (chunk & 3) << 3;         // 0,8,16,24
            async16(&As[chunk * 8], A  + (size_t)(m0 + row) * K + k0 + kc);
            async16(&Bs[chunk * 8], Wt + (size_t)(n0 + row) * K + k0 + kc);
        }
        __syncthreads();
        bf16x8 af[4], bf[4];
#pragma unroll
        for (int f = 0; f < 4; ++f) {
            af[f] = *(const bf16x8*)&As[(wr * 64 + f * 16 + lr) * 32 + kg];
            bf[f] = *(const bf16x8*)&Bs[(wc * 64 + f * 16 + lr) * 32 + kg];
        }
#pragma unroll
        for (int i = 0; i < 4; ++i)
#pragma unroll
            for (int j = 0; j < 4; ++j)
                acc[i][j] = __builtin_amdgcn_mfma_f32_16x16x32_bf16(af[i], bf[j], acc[i][j], 0, 0, 0);
        __syncthreads();
    }

#pragma unroll
    for (int i = 0; i < 4; ++i) {
#pragma unroll
        for (int j = 0; j < 4; ++j) {
            int col = n0 + wc * 64 + j * 16 + lr;
            float bv = bias[col];
#pragma unroll
            for (int v = 0; v < 4; ++v) {
                int row = m0 + wr * 64 + i * 16 + (lane >> 4) * 4 + v;
                float val = acc[i][j][v] + bv;
                size_t idx = (size_t)row * N + col;
                if (MODE == 0) {
                    outF[idx] = val;
                } else if (MODE == 1) {
                    outB[idx] = bfbits(val);
                } else if (MODE == 2) {
                    outB[idx] = bfbits(fmaxf(val, 0.f));
                } else {
                    float t = val + pe[(size_t)(row >> 5) * DM + col];
                    outF[idx] = t;
                    outB[idx] = bfbits(t);
                }
            }
        }
    }
}

// ---------------- V transpose: qkv V-part -> vT[bh][64][512] (bf16, zero-padded) ----
__global__ __launch_bounds__(256) void vtrans_k(const unsigned short* __restrict__ qkv,
                                                unsigned short* __restrict__ vT) {
    __shared__ unsigned short t[32][72];
    const int s0 = blockIdx.x * 32;
    const int bh = blockIdx.y;
    const int b = bh >> 3, h = bh & 7;
    const int tid = threadIdx.x;
    {
        int sl = tid >> 3;                 // 0..31
        int c  = tid & 7;                  // d-chunk
        int s  = s0 + sl;
        uint4 val = {0, 0, 0, 0};
        if (s < SEQ)
            val = *(const uint4*)&qkv[(size_t)(s * BATCH + b) * (3 * DM) + 2 * DM + h * HD + c * 8];
        *(uint4*)&t[sl][c * 8] = val;
    }
    __syncthreads();
    {
        int d  = tid >> 2;                 // 0..63
        int s8 = (tid & 3) * 8;            // 0,8,16,24
        unsigned short v[8];
#pragma unroll
        for (int j = 0; j < 8; ++j) v[j] = t[s8 + j][d];
        *(uint4*)&vT[(size_t)(bh * 64 + d) * 512 + s0 + s8] = *(uint4*)v;
    }
}

// ---------------- sliding-window attention, MFMA, QBLK=64, K/V LDS union ----------------
// Block: 256 thr (4 waves). 64 queries of one (b,h); wave w owns queries w*16..w*16+15.
// Phase 1: stage K (LDS) + zero P + issue V->regs + Q->regs; barrier.
// Phase 2: S^T = K@Q^T (MFMA) -> in-reg softmax; barrier (all waves done with K).
// Phase 3: V regs -> same LDS (union); P -> LDS; barrier.
// Phase 4: O = P@V (MFMA); normalize; store.
#define QBLK  64
#define NIB   8                  // ceil(500/64)
#define KTIL  11                 // key tiles of 16 -> 176 rows
#define KSTR  72                 // K row stride (shorts)
#define VSTR  200                // V^T row stride (shorts)
#define PSTR  200                // P row stride (shorts)

__global__ __launch_bounds__(256, 3) void attn_k(const unsigned short* __restrict__ qkv,
                                                 const unsigned short* __restrict__ vT,
                                                 unsigned short* __restrict__ ob) {
    __shared__ unsigned short KV[12800];       // Kl[176][72] / Vt[64][200] union (25.6 KB)
    __shared__ unsigned short Pl[64 * PSTR];   // 25.6 KB

    const int ib = blockIdx.x & (NIB - 1), bh = blockIdx.x >> 3;
    const int b = bh >> 3, h = bh & 7;
    const int i0 = ib * QBLK;
    const int jbase = max(0, i0 - (WINSZ - 1));
    const int jend  = min(SEQ - 1, i0 + QBLK - 1);
    const int nkeys = jend - jbase + 1;          // <= 163
    const int NT  = (nkeys + 15) >> 4;           // key tiles used
    const int NKS = (nkeys + 31) >> 5;           // PV K-steps used
    const int tid = threadIdx.x, lane = tid & 63, w = tid >> 6;
    const int q15 = lane & 15, grp = lane >> 4;

    // ---- stage K rows (zero-fill beyond nkeys): 176 rows x 8 chunks = 1408 granules ----
#pragma unroll
    for (int it = 0; it < 6; ++it) {
        int g = it * 256 + tid;
        if (g < 1408) {
            int row = g >> 3, c = g & 7;
            uint4 val = {0, 0, 0, 0};
            if (row < nkeys)
                val = *(const uint4*)&qkv[(size_t)((jbase + row) * BATCH + b) * (3 * DM)
                                          + DM + h * HD + c * 8];
            *(uint4*)&KV[row * KSTR + c * 8] = val;
        }
    }
    // ---- zero P: 64*200 shorts = 1600 granules ----
#pragma unroll
    for (int it = 0; it < 7; ++it) {
        int g = it * 256 + tid;
        if (g < 1600) { uint4 z = {0, 0, 0, 0}; *(uint4*)&Pl[g * 8] = z; }
    }
    // ---- V -> regs (issue early; written to LDS after QK phase): 64 x 24 chunks ----
    uint4 vreg[6];
#pragma unroll
    for (int it = 0; it < 6; ++it) {
        int g = it * 256 + tid;                  // 0..1535
        int r = g / 24, c = g - r * 24;
        uint4 val = {0, 0, 0, 0};
        if (c * 8 < nkeys && jbase + c * 8 + 8 <= 512)
            val = *(const uint4*)&vT[(size_t)(bh * 64 + r) * 512 + jbase + c * 8];
        vreg[it] = val;
    }
    // ---- Q -> regs (B-fragments) ----
    bf16x8 qav, qbv;
    {
        int iq = min(i0 + w * 16 + q15, SEQ - 1);
        size_t qrow = (size_t)(iq * BATCH + b) * (3 * DM) + h * HD;
        uint4 a = *(const uint4*)&qkv[qrow + grp * 8];
        uint4 c = *(const uint4*)&qkv[qrow + 32 + grp * 8];
        qav = __builtin_bit_cast(bf16x8, a);
        qbv = __builtin_bit_cast(bf16x8, c);
    }
    __syncthreads();

    // ---- QK^T (S^T layout: row=key, col=query) + mask ----
    const int i = i0 + w * 16 + q15;             // this lane's query (as col)
    float sc[KTIL][4];
#pragma unroll
    for (int t = 0; t < KTIL; ++t) {
        if (t >= NT) continue;                   // uniform
        f32x4 acc = {};
        int row = t * 16 + q15;                  // key row (A-frag: lane&15)
        bf16x8 kf0 = *(const bf16x8*)&KV[row * KSTR + grp * 8];
        acc = __builtin_amdgcn_mfma_f32_16x16x32_bf16(kf0, qav, acc, 0, 0, 0);
        bf16x8 kf1 = *(const bf16x8*)&KV[row * KSTR + 32 + grp * 8];
        acc = __builtin_amdgcn_mfma_f32_16x16x32_bf16(kf1, qbv, acc, 0, 0, 0);
#pragma unroll
        for (int v = 0; v < 4; ++v) {
            int key = jbase + t * 16 + grp * 4 + v;   // C-layout row
            bool valid = (key <= i) && (key > i - WINSZ);
            sc[t][v] = valid ? acc[v] * 0.125f : -1e30f;
        }
    }
    // ---- softmax over keys (local + xor16 + xor32: lanes {q15,+16,+32,+48}) ----
    float m = -1e30f;
#pragma unroll
    for (int t = 0; t < KTIL; ++t) {
        if (t >= NT) continue;
#pragma unroll
        for (int v = 0; v < 4; ++v) m = fmaxf(m, sc[t][v]);
    }
    m = fmaxf(m, __shfl_xor(m, 16));
    m = fmaxf(m, __shfl_xor(m, 32));
    float sum = 0.f;
#pragma unroll
    for (int t = 0; t < KTIL; ++t) {
        if (t >= NT) continue;
#pragma unroll
        for (int v = 0; v < 4; ++v) {
            float p = __expf(sc[t][v] - m);
            sc[t][v] = p;
            sum += p;
        }
    }
    sum += __shfl_xor(sum, 16);
    sum += __shfl_xor(sum, 32);

    __syncthreads();   // all waves done reading K from the union buffer

    // ---- V regs -> LDS (union with K) ----
#pragma unroll
    for (int it = 0; it < 6; ++it) {
        int g = it * 256 + tid;
        int r = g / 24, c = g - r * 24;
        *(uint4*)&KV[r * VSTR + c * 8] = vreg[it];
    }
    // ---- P -> LDS (bf16; row = query, col = key) ----
#pragma unroll
    for (int t = 0; t < KTIL; ++t) {
        if (t >= NT) continue;
        uint2 pk;
        pk.x = pack2(sc[t][0], sc[t][1]);
        pk.y = pack2(sc[t][2], sc[t][3]);
        *(uint2*)&Pl[(w * 16 + q15) * PSTR + t * 16 + grp * 4] = pk;
    }
    __syncthreads();   // Vt ready (P is own-wave)

    // ---- PV: O = P @ V ; A-frag = P rows, B-frag = Vt rows (GEMM-style) ----
    f32x4 oacc[4] = {};
#pragma unroll
    for (int ks = 0; ks < 6; ++ks) {
        if (ks >= NKS) continue;                 // uniform
        bf16x8 pf = *(const bf16x8*)&Pl[(w * 16 + q15) * PSTR + ks * 32 + grp * 8];
#pragma unroll
        for (int dt = 0; dt < 4; ++dt) {
            bf16x8 vf = *(const bf16x8*)&KV[(dt * 16 + q15) * VSTR + ks * 32 + grp * 8];
            oacc[dt] = __builtin_amdgcn_mfma_f32_16x16x32_bf16(pf, vf, oacc[dt], 0, 0, 0);
        }
    }

    // ---- normalize + store (C row = grp*4+v = query; col = q15 = d) ----
#pragma unroll
    for (int v = 0; v < 4; ++v) {
        float rsv = 1.0f / __shfl(sum, grp * 4 + v);
        int irow = i0 + w * 16 + grp * 4 + v;
        if (irow < SEQ) {
            size_t base = (size_t)(irow * BATCH + b) * DM + h * HD + q15;
#pragma unroll
            for (int dt = 0; dt < 4; ++dt)
                ob[base + dt * 16] = bfbits(oacc[dt][v] * rsv);
        }
    }
}

// ---------------- residual + layernorm (wave per row); yin is bf16 ----------------
__global__ __launch_bounds__(256) void ln_k(const float* __restrict__ hin,
                                            const unsigned short* __restrict__ yin,
                                            const float* __restrict__ sc,
                                            const float* __restrict__ bi,
                                            float* __restrict__ hout,
                                            unsigned short* __restrict__ hb) {
    int row = blockIdx.x * 4 + (threadIdx.x >> 6);
    int lane = threadIdx.x & 63;
    size_t base = (size_t)row * DM + lane * 8;
    float4 a0 = *(const float4*)&hin[base], a1 = *(const float4*)&hin[base + 4];
    uint4 yw = *(const uint4*)&yin[base];
    float x[8] = {a0.x + blo(yw.x), a0.y + bhi(yw.x), a0.z + blo(yw.y), a0.w + bhi(yw.y),
                  a1.x + blo(yw.z), a1.y + bhi(yw.z), a1.z + blo(yw.w), a1.w + bhi(yw.w)};
    float s = 0.f;
#pragma unroll
    for (int k = 0; k < 8; ++k) s += x[k];
#pragma unroll
    for (int off = 32; off; off >>= 1) s += __shfl_xor(s, off);
    float mean = s * (1.f / DM);
    float q = 0.f;
#pragma unroll
    for (int k = 0; k < 8; ++k) { float d = x[k] - mean; q = fmaf(d, d, q); }
#pragma unroll
    for (int off = 32; off; off >>= 1) q += __shfl_xor(q, off);
    float rstd = rsqrtf(q * (1.f / DM) + 1e-5f);
    float4 s0 = *(const float4*)&sc[lane * 8], s1 = *(const float4*)&sc[lane * 8 + 4];
    float4 b0 = *(const float4*)&bi[lane * 8], b1 = *(const float4*)&bi[lane * 8 + 4];
    float o[8];
    o[0] = (x[0] - mean) * rstd * s0.x + b0.x;  o[1] = (x[1] - mean) * rstd * s0.y + b0.y;
    o[2] = (x[2] - mean) * rstd * s0.z + b0.z;  o[3] = (x[3] - mean) * rstd * s0.w + b0.w;
    o[4] = (x[4] - mean) * rstd * s1.x + b1.x;  o[5] = (x[5] - mean) * rstd * s1.y + b1.y;
    o[6] = (x[6] - mean) * rstd * s1.z + b1.z;  o[7] = (x[7] - mean) * rstd * s1.w + b1.w;
    float4 w0 = {o[0], o[1], o[2], o[3]}, w1 = {o[4], o[5], o[6], o[7]};
    *(float4*)&hout[base] = w0;
    *(float4*)&hout[base + 4] = w1;
    uint4 pk = {pack2(o[0], o[1]), pack2(o[2], o[3]), pack2(o[4], o[5]), pack2(o[6], o[7])};
    *(uint4*)&hb[base] = pk;
}

// ---------------- host launch ----------------
extern "C" void kernel_launch(void* const* d_in, const int* in_sizes, int n_in,
                              void* d_out, int out_size, void* d_ws, size_t ws_size,
                              hipStream_t stream) {
    const float* x     = (const float*)d_in[0];
    const float* Wemb  = (const float*)d_in[1];
    const float* bemb  = (const float*)d_in[2];
    const float* Wq    = (const float*)d_in[3];
    const float* bq    = (const float*)d_in[4];
    const float* Wk    = (const float*)d_in[5];
    const float* bk    = (const float*)d_in[6];
    const float* Wv    = (const float*)d_in[7];
    const float* bv    = (const float*)d_in[8];
    const float* Wo    = (const float*)d_in[9];
    const float* bo    = (const float*)d_in[10];
    const float* ln1s  = (const float*)d_in[11];
    const float* ln1b  = (const float*)d_in[12];
    const float* W1    = (const float*)d_in[13];
    const float* b1    = (const float*)d_in[14];
    const float* W2    = (const float*)d_in[15];
    const float* b2    = (const float*)d_in[16];
    const float* ln2s  = (const float*)d_in[17];
    const float* ln2b  = (const float*)d_in[18];

    char* p = (char*)d_ws;
    auto carve = [&](size_t bytes) { char* r = p; p += (bytes + 255) & ~(size_t)255; return r; };

    unsigned short* wt_emb = (unsigned short*)carve((size_t)DM * DIN * 2);
    unsigned short* wt_qkv = (unsigned short*)carve((size_t)NL * 3 * DM * DM * 2);
    unsigned short* wt_o   = (unsigned short*)carve((size_t)NL * DM * DM * 2);
    unsigned short* wt_1   = (unsigned short*)carve((size_t)NL * DF * DM * 2);
    unsigned short* wt_2   = (unsigned short*)carve((size_t)NL * DM * DF * 2);
    float*          biasq  = (float*)carve((size_t)NL * 3 * DM * 4);
    float*          pe     = (float*)carve((size_t)SEQ * DM * 4);
    unsigned short* xb     = (unsigned short*)carve((size_t)ROWS * DIN * 2);
    float*          h      = (float*)carve((size_t)ROWS * DM * 4);
    unsigned short* hb     = (unsigned short*)carve((size_t)ROWS * DM * 2);
    unsigned short* ob     = (unsigned short*)carve((size_t)ROWS * DM * 2);
    unsigned short* t0b    = (unsigned short*)carve((size_t)ROWS * DM * 2);
    unsigned short* vT     = (unsigned short*)carve((size_t)BATCH * NH * 64 * 512 * 2 + 1024);
    unsigned short* qkv    = (unsigned short*)carve((size_t)ROWS * DF * 2); // aliased: qkv (x1536) / f1 (x2048)
    unsigned short* f1     = qkv;

    dim3 blk256(256);

    // weight transposes
    tcast_k<<<dim3(DM / 32, DIN / 32), dim3(32, 8), 0, stream>>>(Wemb, wt_emb, DIN, DM);
    for (int l = 0; l < NL; ++l) {
        tcast_k<<<dim3(DM / 32, DM / 32), dim3(32, 8), 0, stream>>>(Wq + (size_t)l * DM * DM, wt_qkv + (size_t)l * 3 * DM * DM, DM, DM);
        tcast_k<<<dim3(DM / 32, DM / 32), dim3(32, 8), 0, stream>>>(Wk + (size_t)l * DM * DM, wt_qkv + (size_t)l * 3 * DM * DM + (size_t)DM * DM, DM, DM);
        tcast_k<<<dim3(DM / 32, DM / 32), dim3(32, 8), 0, stream>>>(Wv + (size_t)l * DM * DM, wt_qkv + (size_t)l * 3 * DM * DM + (size_t)2 * DM * DM, DM, DM);
        tcast_k<<<dim3(DM / 32, DM / 32), dim3(32, 8), 0, stream>>>(Wo + (size_t)l * DM * DM, wt_o + (size_t)l * DM * DM, DM, DM);
        tcast_k<<<dim3(DF / 32, DM / 32), dim3(32, 8), 0, stream>>>(W1 + (size_t)l * DM * DF, wt_1 + (size_t)l * DF * DM, DM, DF);
        tcast_k<<<dim3(DM / 32, DF / 32), dim3(32, 8), 0, stream>>>(W2 + (size_t)l * DF * DM, wt_2 + (size_t)l * DM * DF, DF, DM);
    }
    prep_k<<<dim3((SEQ * DM + 255) / 256), blk256, 0, stream>>>(bq, bk, bv, biasq, pe);
    xcast_k<<<dim3(ROWS * DIN / 4 / 256), blk256, 0, stream>>>(x, xb, ROWS * DIN);

    // embedding + posenc
    gemm_k<3><<<dim3(ROWS / 128, DM / 128), blk256, 0, stream>>>(xb, wt_emb, bemb, h, hb, pe, ROWS, DM, DIN);

    for (int l = 0; l < NL; ++l) {
        // QKV
        gemm_k<1><<<dim3(ROWS / 128, 3 * DM / 128), blk256, 0, stream>>>(
            hb, wt_qkv + (size_t)l * 3 * DM * DM, biasq + (size_t)l * 3 * DM,
            nullptr, qkv, nullptr, ROWS, 3 * DM, DM);
        // V transpose -> vT[bh][64][512] (zero-padded)
        vtrans_k<<<dim3(16, BATCH * NH), blk256, 0, stream>>>(qkv, vT);
        // attention (MFMA, QBLK=64)
        attn_k<<<dim3(BATCH * NH * NIB), blk256, 0, stream>>>(qkv, vT, ob);
        // O-proj -> t0b (bf16)
        gemm_k<1><<<dim3(ROWS / 128, DM / 128), blk256, 0, stream>>>(
            ob, wt_o + (size_t)l * DM * DM, bo + (size_t)l * DM,
            nullptr, t0b, nullptr, ROWS, DM, DM);
        // LN1: h = LN(h + t0b)
        ln_k<<<dim3(ROWS / 4), blk256, 0, stream>>>(h, t0b, ln1s + (size_t)l * DM, ln1b + (size_t)l * DM, h, hb);
        // FFN1 -> f1 (relu, bf16)
        gemm_k<2><<<dim3(ROWS / 128, DF / 128), blk256, 0, stream>>>(
            hb, wt_1 + (size_t)l * DF * DM, b1 + (size_t)l * DF,
            nullptr, f1, nullptr, ROWS, DF, DM);
        // FFN2 -> t0b (bf16)
        gemm_k<1><<<dim3(ROWS / 128, DM / 128), blk256, 0, stream>>>(
            f1, wt_2 + (size_t)l * DM * DF, b2 + (size_t)l * DM,
            nullptr, t0b, nullptr, ROWS, DM, DF);
        // LN2: h = LN(h + t0b) ; final layer writes d_out
        float* hdst = (l == NL - 1) ? (float*)d_out : h;
        ln_k<<<dim3(ROWS / 4), blk256, 0, stream>>>(h, t0b, ln2s + (size_t)l * DM, ln2b + (size_t)l * DM, hdst, hb);
    }
}